// Round 2
// baseline (11953.923 us; speedup 1.0000x reference)
//
#include <hip/hip_runtime.h>

// ---------------------------------------------------------------------------
// GeneralGNN: 4-layer GCN (skip='all') + MLP head. fp32 baseline, ws <= 257MB.
//   agg = D^-1/2 (A+I) D^-1/2 (emb @ W)
// factored: g = dinv*(emb@W); t[dst] += g[src] (atomics, real edges only);
//           h = relu(dinv*(t+g) + b)
// Workspace (floats): emb[n*512] | g[n*128] | deg[n] | dinv[n]   (256.8 MB)
// t = d_out during convs; layer-3 combine writes h4 in-place into d_out.
// post_w1 (K=640) = accumulating 2-pass GEMM: emb[:, :512] then h4.
// ---------------------------------------------------------------------------

__global__ __launch_bounds__(256) void zero_buf(float* p, long long nfloat) {
    long long i = (long long)blockIdx.x * 256 + threadIdx.x;
    if (i < nfloat) p[i] = 0.0f;
}

__global__ __launch_bounds__(256) void deg_init(float* deg, int n) {
    int i = blockIdx.x * 256 + threadIdx.x;
    if (i < n) deg[i] = 1.0f;  // self-loop
}

__global__ __launch_bounds__(256) void deg_scatter(const int* __restrict__ ei, float* deg, int E) {
    int e = blockIdx.x * 256 + threadIdx.x;
    if (e < E) atomicAdd(&deg[ei[E + e]], 1.0f);  // dst = ei[1][e]
}

__global__ __launch_bounds__(256) void make_dinv(const float* __restrict__ deg, float* dinv, int n) {
    int i = blockIdx.x * 256 + threadIdx.x;
    if (i < n) {
        float d = deg[i];
        dinv[i] = d > 0.0f ? rsqrtf(d) : 0.0f;
    }
}

// C[M,N] = act( rowscale * (A[M,K] @ W[K,N]) + bias + (accum ? C : 0) )
// act: 0=none, 1=relu, 2=leakyrelu(0.1). Tile: 64 rows x 128 cols per block.
__global__ __launch_bounds__(256) void gemm_f32(
    const float* __restrict__ A, int lda,
    const float* __restrict__ W, int ldw,
    const float* __restrict__ bias,
    const float* __restrict__ rowscale,
    float* __restrict__ C, int ldc,
    int M, int K, int act, int accum)
{
    __shared__ float As[64][20];    // pitch 20 floats (80B, 16B-aligned rows)
    __shared__ float Ws[16][128];

    const int t = threadIdx.x;
    const int row0 = blockIdx.x * 64;
    const int colbase = blockIdx.y * 128;
    const int r0 = (t >> 5) * 8;        // 8 row-groups
    const int c0 = (t & 31) * 4;        // 32 col-groups of 4

    float acc[8][4];
#pragma unroll
    for (int r = 0; r < 8; ++r)
#pragma unroll
        for (int c = 0; c < 4; ++c) acc[r][c] = 0.0f;

    const int arow = t >> 2;            // 0..63
    const int acol = (t & 3) * 4;       // 0,4,8,12

    for (int k0 = 0; k0 < K; k0 += 16) {
        // stage A tile (64 x 16)
        float4 av = make_float4(0.f, 0.f, 0.f, 0.f);
        int gr = row0 + arow;
        if (gr < M) av = *(const float4*)&A[(size_t)gr * lda + k0 + acol];
        *(float4*)&As[arow][acol] = av;
        // stage W tile (16 x 128)
#pragma unroll
        for (int i = 0; i < 2; ++i) {
            int idx = t + i * 256;          // 0..511
            int wr = idx >> 5;              // 0..15
            int wc = (idx & 31) * 4;        // 0..124
            *(float4*)&Ws[wr][wc] = *(const float4*)&W[(size_t)(k0 + wr) * ldw + colbase + wc];
        }
        __syncthreads();
#pragma unroll
        for (int kk = 0; kk < 16; ++kk) {
            float4 w = *(float4*)&Ws[kk][c0];
#pragma unroll
            for (int r = 0; r < 8; ++r) {
                float a = As[r0 + r][kk];
                acc[r][0] = fmaf(a, w.x, acc[r][0]);
                acc[r][1] = fmaf(a, w.y, acc[r][1]);
                acc[r][2] = fmaf(a, w.z, acc[r][2]);
                acc[r][3] = fmaf(a, w.w, acc[r][3]);
            }
        }
        __syncthreads();
    }

    float4 bv = make_float4(0.f, 0.f, 0.f, 0.f);
    if (bias) bv = *(const float4*)&bias[colbase + c0];
#pragma unroll
    for (int r = 0; r < 8; ++r) {
        int gr = row0 + r0 + r;
        if (gr >= M) continue;
        float s = rowscale ? rowscale[gr] : 1.0f;
        float4 o;
        o.x = fmaf(acc[r][0], s, bv.x);
        o.y = fmaf(acc[r][1], s, bv.y);
        o.z = fmaf(acc[r][2], s, bv.z);
        o.w = fmaf(acc[r][3], s, bv.w);
        float* cp = &C[(size_t)gr * ldc + colbase + c0];
        if (accum) {
            float4 c = *(float4*)cp;
            o.x += c.x; o.y += c.y; o.z += c.z; o.w += c.w;
        }
        if (act == 1) {
            o.x = fmaxf(o.x, 0.f); o.y = fmaxf(o.y, 0.f);
            o.z = fmaxf(o.z, 0.f); o.w = fmaxf(o.w, 0.f);
        } else if (act == 2) {
            o.x = o.x > 0.f ? o.x : 0.1f * o.x;
            o.y = o.y > 0.f ? o.y : 0.1f * o.y;
            o.z = o.z > 0.f ? o.z : 0.1f * o.z;
            o.w = o.w > 0.f ? o.w : 0.1f * o.w;
        }
        *(float4*)cp = o;
    }
}

// t[dst] += g[src] for every real edge; one thread = one edge x 4 floats
__global__ __launch_bounds__(256) void scatter_add(
    const int* __restrict__ ei, const float* __restrict__ g, float* t, int E)
{
    long long tid = (long long)blockIdx.x * 256 + threadIdx.x;
    int e = (int)(tid >> 5);
    int part = (int)(tid & 31);
    if (e >= E) return;
    int src = ei[e];
    int dst = ei[E + e];
    float4 v = *(const float4*)&g[(size_t)src * 128 + part * 4];
    float* tp = &t[(size_t)dst * 128 + part * 4];
    atomicAdd(tp + 0, v.x);
    atomicAdd(tp + 1, v.y);
    atomicAdd(tp + 2, v.z);
    atomicAdd(tp + 3, v.w);
}

// out[i,:] = relu(dinv[i]*(t[i,:]+g[i,:]) + b); optionally re-zero t for next
// layer. Safe when out == t (read-before-write, thread-private elements).
__global__ __launch_bounds__(256) void combine_relu(
    float* __restrict__ t, const float* __restrict__ g,
    const float* __restrict__ dinv, const float* __restrict__ b,
    float* __restrict__ out, int ldo, int n, int zero_after)
{
    long long tid = (long long)blockIdx.x * 256 + threadIdx.x;
    int i = (int)(tid >> 5);
    int part = (int)(tid & 31);
    if (i >= n) return;
    int d = part * 4;
    float s = dinv[i];
    float* tp = &t[(size_t)i * 128 + d];
    float4 tv = *(float4*)tp;
    float4 gv = *(const float4*)&g[(size_t)i * 128 + d];
    float4 bv = *(const float4*)&b[d];
    float4 o;
    o.x = fmaxf(fmaf(s, tv.x + gv.x, bv.x), 0.f);
    o.y = fmaxf(fmaf(s, tv.y + gv.y, bv.y), 0.f);
    o.z = fmaxf(fmaf(s, tv.z + gv.z, bv.z), 0.f);
    o.w = fmaxf(fmaf(s, tv.w + gv.w, bv.w), 0.f);
    *(float4*)&out[(size_t)i * ldo + d] = o;
    if (zero_after) *(float4*)tp = make_float4(0.f, 0.f, 0.f, 0.f);
}

extern "C" void kernel_launch(void* const* d_in, const int* in_sizes, int n_in,
                              void* d_out, int out_size, void* d_ws, size_t ws_size,
                              hipStream_t stream) {
    const float* x      = (const float*)d_in[0];
    const int*   ei     = (const int*)d_in[1];
    const float* pre_w  = (const float*)d_in[2];
    const float* pre_b  = (const float*)d_in[3];
    const float* conv_w[4] = {(const float*)d_in[4], (const float*)d_in[6],
                              (const float*)d_in[8], (const float*)d_in[10]};
    const float* conv_b[4] = {(const float*)d_in[5], (const float*)d_in[7],
                              (const float*)d_in[9], (const float*)d_in[11]};
    const float* post_w1 = (const float*)d_in[12];
    const float* post_b1 = (const float*)d_in[13];
    const float* post_w2 = (const float*)d_in[14];
    const float* post_b2 = (const float*)d_in[15];
    const float* post_w3 = (const float*)d_in[16];
    const float* post_b3 = (const float*)d_in[17];
    const float* post_w4 = (const float*)d_in[18];
    const float* post_b4 = (const float*)d_in[19];

    const int n = in_sizes[0] / 128;    // 100000
    const int E = in_sizes[1] / 2;      // 1600000

    // workspace: emb[n*512] | g[n*128] | deg[n] | dinv[n]  = n*642 floats
    size_t need = (size_t)n * 642 * sizeof(float);
    if (ws_size < need) return;  // diagnostic: zeros output -> absmax 1.078 signature

    float* emb  = (float*)d_ws;                  // h0..h3, ld=512
    float* g    = emb + (size_t)n * 512;
    float* deg  = g + (size_t)n * 128;
    float* dinv = deg + n;
    float* tbuf = (float*)d_out;                 // scatter target; becomes h4
    float* h1   = g;                             // post overlays (dead buffers)
    float* h2   = (float*)d_out;
    float* h3   = emb;

    // init: t = 0, degrees
    zero_buf<<<(int)(((long long)n * 128 + 255) / 256), 256, 0, stream>>>(tbuf, (long long)n * 128);
    deg_init<<<(n + 255) / 256, 256, 0, stream>>>(deg, n);
    deg_scatter<<<(E + 255) / 256, 256, 0, stream>>>(ei, deg, E);
    make_dinv<<<(n + 255) / 256, 256, 0, stream>>>(deg, dinv, n);

    auto gemm = [&](const float* A, int lda, const float* W, int ldw,
                    const float* bias, const float* rs,
                    float* C, int ldc, int M, int K, int N, int act, int accum) {
        dim3 grid((M + 63) / 64, N / 128);
        gemm_f32<<<grid, 256, 0, stream>>>(A, lda, W, ldw, bias, rs, C, ldc, M, K, act, accum);
    };

    // pre_mp: emb[:, 0:128] = x @ pre_w + pre_b
    gemm(x, 128, pre_w, 128, pre_b, nullptr, emb, 512, n, 128, 128, 0, 0);

    for (int l = 0; l < 4; ++l) {
        int K = 128 * (l + 1);
        // g = dinv * (emb[:, :K] @ conv_w[l])
        gemm(emb, 512, conv_w[l], 128, nullptr, dinv, g, 128, n, K, 128, 0, 0);
        // t[dst] += g[src]
        scatter_add<<<(int)(((long long)E * 32 + 255) / 256), 256, 0, stream>>>(ei, g, tbuf, E);
        // h_{l+1} = relu(dinv*(t+g)+b) -> emb col block (l<3) or in-place d_out (l=3)
        float* out = (l < 3) ? (emb + (size_t)128 * (l + 1)) : tbuf;
        int ldo = (l < 3) ? 512 : 128;
        combine_relu<<<(int)(((long long)n * 32 + 255) / 256), 256, 0, stream>>>(
            tbuf, g, dinv, conv_b[l], out, ldo, n, (l < 3) ? 1 : 0);
    }

    // post_mp
    // h1 = LeakyReLU( emb[:, :512]@W1[:512] + h4@W1[512:] + b1 ), two passes
    gemm(emb, 512, post_w1, 128, nullptr, nullptr, h1, 128, n, 512, 128, 0, 0);
    gemm(tbuf, 128, post_w1 + (size_t)512 * 128, 128, post_b1, nullptr, h1, 128, n, 128, 128, 2, 1);
    // h2 = relu(h1@W2 + b2)   (d_out; h4 dead)
    gemm(h1, 128, post_w2, 128, post_b2, nullptr, h2, 128, n, 128, 128, 1, 0);
    // h3 = relu(h2@W3 + b3)   N=256, overlays emb (dead)
    gemm(h2, 128, post_w3, 256, post_b3, nullptr, h3, 256, n, 128, 256, 1, 0);
    // out = h3@W4 + b4
    gemm(h3, 256, post_w4, 128, post_b4, nullptr, (float*)d_out, 128, n, 256, 128, 0, 0);
}

// Round 3
// 1841.815 us; speedup vs baseline: 6.4903x; 6.4903x over previous
//
#include <hip/hip_runtime.h>

// ---------------------------------------------------------------------------
// GeneralGNN: 4-layer GCN (skip='all') + MLP head.
// Round 2: atomic scatter -> CSR + fused gather/combine.
//   g = dinv * (emb @ W)   (GEMM epilogue rowscale)
//   h = relu(dinv * (sum_{src->i} g[src] + g[i]) + b)   (gather, fused)
// Workspace (bytes): emb n*512f | g n*128f | dinv n f | rp n i | csr E i
//                    = 263.2 MB
// ---------------------------------------------------------------------------

__global__ __launch_bounds__(256) void zero_int(int* p, int n) {
    int i = blockIdx.x * 256 + threadIdx.x;
    if (i < n) p[i] = 0;
}

// in-degree histogram: cnt[dst]++
__global__ __launch_bounds__(256) void hist_dst(const int* __restrict__ ei, int* cnt, int E) {
    int e = blockIdx.x * 256 + threadIdx.x;
    if (e < E) atomicAdd(&cnt[ei[E + e]], 1);
}

// single-block exclusive scan of cnt[n] -> rp[n]
__global__ __launch_bounds__(1024) void scan_excl(const int* __restrict__ cnt, int* __restrict__ rp, int n) {
    __shared__ int sums[1024];
    const int t = threadIdx.x;
    const int chunk = (n + 1023) / 1024;
    const int lo = t * chunk;
    const int hi = min(lo + chunk, n);
    int s = 0;
    for (int i = lo; i < hi; ++i) s += cnt[i];
    sums[t] = s;
    __syncthreads();
    for (int off = 1; off < 1024; off <<= 1) {
        int v = (t >= off) ? sums[t - off] : 0;
        __syncthreads();
        sums[t] += v;
        __syncthreads();
    }
    int base = (t == 0) ? 0 : sums[t - 1];
    for (int i = lo; i < hi; ++i) { rp[i] = base; base += cnt[i]; }
}

// fill CSR using rp as the running cursor (shifted-row_ptr trick):
// after this kernel rp[i] == end of row i == start of row i+1.
__global__ __launch_bounds__(256) void csr_fill(const int* __restrict__ ei, int* rp, int* csr, int E) {
    int e = blockIdx.x * 256 + threadIdx.x;
    if (e < E) {
        int pos = atomicAdd(&rp[ei[E + e]], 1);
        csr[pos] = ei[e];
    }
}

// dinv[i] = rsqrt(indeg + 1)  with  indeg = rp[i] - (i ? rp[i-1] : 0)
__global__ __launch_bounds__(256) void make_dinv(const int* __restrict__ rp, float* dinv, int n) {
    int i = blockIdx.x * 256 + threadIdx.x;
    if (i < n) {
        int start = i ? rp[i - 1] : 0;
        dinv[i] = rsqrtf((float)(rp[i] - start + 1));
    }
}

// C[M,N] = act( rowscale * (A[M,K] @ W[K,N]) + bias + (accum ? C : 0) )
// act: 0=none, 1=relu, 2=leakyrelu(0.1). Tile: 64 rows x 128 cols per block.
__global__ __launch_bounds__(256) void gemm_f32(
    const float* __restrict__ A, int lda,
    const float* __restrict__ W, int ldw,
    const float* __restrict__ bias,
    const float* __restrict__ rowscale,
    float* __restrict__ C, int ldc,
    int M, int K, int act, int accum)
{
    __shared__ float As[64][20];
    __shared__ float Ws[16][128];

    const int t = threadIdx.x;
    const int row0 = blockIdx.x * 64;
    const int colbase = blockIdx.y * 128;
    const int r0 = (t >> 5) * 8;
    const int c0 = (t & 31) * 4;

    float acc[8][4];
#pragma unroll
    for (int r = 0; r < 8; ++r)
#pragma unroll
        for (int c = 0; c < 4; ++c) acc[r][c] = 0.0f;

    const int arow = t >> 2;
    const int acol = (t & 3) * 4;

    for (int k0 = 0; k0 < K; k0 += 16) {
        float4 av = make_float4(0.f, 0.f, 0.f, 0.f);
        int gr = row0 + arow;
        if (gr < M) av = *(const float4*)&A[(size_t)gr * lda + k0 + acol];
        *(float4*)&As[arow][acol] = av;
#pragma unroll
        for (int i = 0; i < 2; ++i) {
            int idx = t + i * 256;
            int wr = idx >> 5;
            int wc = (idx & 31) * 4;
            *(float4*)&Ws[wr][wc] = *(const float4*)&W[(size_t)(k0 + wr) * ldw + colbase + wc];
        }
        __syncthreads();
#pragma unroll
        for (int kk = 0; kk < 16; ++kk) {
            float4 w = *(float4*)&Ws[kk][c0];
#pragma unroll
            for (int r = 0; r < 8; ++r) {
                float a = As[r0 + r][kk];
                acc[r][0] = fmaf(a, w.x, acc[r][0]);
                acc[r][1] = fmaf(a, w.y, acc[r][1]);
                acc[r][2] = fmaf(a, w.z, acc[r][2]);
                acc[r][3] = fmaf(a, w.w, acc[r][3]);
            }
        }
        __syncthreads();
    }

    float4 bv = make_float4(0.f, 0.f, 0.f, 0.f);
    if (bias) bv = *(const float4*)&bias[colbase + c0];
#pragma unroll
    for (int r = 0; r < 8; ++r) {
        int gr = row0 + r0 + r;
        if (gr >= M) continue;
        float s = rowscale ? rowscale[gr] : 1.0f;
        float4 o;
        o.x = fmaf(acc[r][0], s, bv.x);
        o.y = fmaf(acc[r][1], s, bv.y);
        o.z = fmaf(acc[r][2], s, bv.z);
        o.w = fmaf(acc[r][3], s, bv.w);
        float* cp = &C[(size_t)gr * ldc + colbase + c0];
        if (accum) {
            float4 c = *(float4*)cp;
            o.x += c.x; o.y += c.y; o.z += c.z; o.w += c.w;
        }
        if (act == 1) {
            o.x = fmaxf(o.x, 0.f); o.y = fmaxf(o.y, 0.f);
            o.z = fmaxf(o.z, 0.f); o.w = fmaxf(o.w, 0.f);
        } else if (act == 2) {
            o.x = o.x > 0.f ? o.x : 0.1f * o.x;
            o.y = o.y > 0.f ? o.y : 0.1f * o.y;
            o.z = o.z > 0.f ? o.z : 0.1f * o.z;
            o.w = o.w > 0.f ? o.w : 0.1f * o.w;
        }
        *(float4*)cp = o;
    }
}

// One 64-lane wave per dst node, float2 per lane (128 cols).
// out[i,:] = relu( dinv[i] * (sum_{j in row i} g[csr[j]] + g[i]) + b )
__global__ __launch_bounds__(256) void gcn_gather(
    const int* __restrict__ rp, const int* __restrict__ csr,
    const float* __restrict__ g, const float* __restrict__ dinv,
    const float* __restrict__ b,
    float* __restrict__ out, int ldo, int n)
{
    const int wave = (int)(((long long)blockIdx.x * 256 + threadIdx.x) >> 6);
    const int lane = threadIdx.x & 63;
    if (wave >= n) return;
    const int i = wave;
    const int start = i ? rp[i - 1] : 0;
    const int end = rp[i];

    const int d = lane * 2;
    float2 acc = *(const float2*)&g[(size_t)i * 128 + d];  // self-loop term

    int src_next = (start < end) ? csr[start] : 0;
    for (int j = start; j < end; ++j) {
        int src = src_next;
        if (j + 1 < end) src_next = csr[j + 1];
        float2 v = *(const float2*)&g[(size_t)src * 128 + d];
        acc.x += v.x;
        acc.y += v.y;
    }

    const float s = dinv[i];
    float2 bv = *(const float2*)&b[d];
    float2 o;
    o.x = fmaxf(fmaf(s, acc.x, bv.x), 0.f);
    o.y = fmaxf(fmaf(s, acc.y, bv.y), 0.f);
    *(float2*)&out[(size_t)i * ldo + d] = o;
}

extern "C" void kernel_launch(void* const* d_in, const int* in_sizes, int n_in,
                              void* d_out, int out_size, void* d_ws, size_t ws_size,
                              hipStream_t stream) {
    const float* x      = (const float*)d_in[0];
    const int*   ei     = (const int*)d_in[1];
    const float* pre_w  = (const float*)d_in[2];
    const float* pre_b  = (const float*)d_in[3];
    const float* conv_w[4] = {(const float*)d_in[4], (const float*)d_in[6],
                              (const float*)d_in[8], (const float*)d_in[10]};
    const float* conv_b[4] = {(const float*)d_in[5], (const float*)d_in[7],
                              (const float*)d_in[9], (const float*)d_in[11]};
    const float* post_w1 = (const float*)d_in[12];
    const float* post_b1 = (const float*)d_in[13];
    const float* post_w2 = (const float*)d_in[14];
    const float* post_b2 = (const float*)d_in[15];
    const float* post_w3 = (const float*)d_in[16];
    const float* post_b3 = (const float*)d_in[17];
    const float* post_w4 = (const float*)d_in[18];
    const float* post_b4 = (const float*)d_in[19];

    const int n = in_sizes[0] / 128;    // 100000
    const int E = in_sizes[1] / 2;      // 1600000

    // ws: emb n*512 f | g n*128 f | dinv n f (cnt overlay) | rp n i | csr E i
    size_t need = ((size_t)n * 512 + (size_t)n * 128 + n + n + E) * 4;
    if (ws_size < need) return;  // diagnostic early-out

    float* emb  = (float*)d_ws;                      // h0..h3, ld=512
    float* g    = emb + (size_t)n * 512;
    float* dinv = g + (size_t)n * 128;               // also cnt (int) overlay
    int*   rp   = (int*)(dinv + n);
    int*   csr  = rp + n;
    int*   cnt  = (int*)dinv;

    float* h4 = (float*)d_out;   // layer-3 gather output
    float* h1 = g;               // post overlays (dead buffers)
    float* h2 = (float*)d_out;
    float* h3 = emb;

    // ---- CSR build ----
    zero_int<<<(n + 255) / 256, 256, 0, stream>>>(cnt, n);
    hist_dst<<<(E + 255) / 256, 256, 0, stream>>>(ei, cnt, E);
    scan_excl<<<1, 1024, 0, stream>>>(cnt, rp, n);
    csr_fill<<<(E + 255) / 256, 256, 0, stream>>>(ei, rp, csr, E);
    make_dinv<<<(n + 255) / 256, 256, 0, stream>>>(rp, dinv, n);

    auto gemm = [&](const float* A, int lda, const float* W, int ldw,
                    const float* bias, const float* rs,
                    float* C, int ldc, int M, int K, int N, int act, int accum) {
        dim3 grid((M + 63) / 64, N / 128);
        gemm_f32<<<grid, 256, 0, stream>>>(A, lda, W, ldw, bias, rs, C, ldc, M, K, act, accum);
    };

    // pre_mp: emb[:, 0:128] = x @ pre_w + pre_b
    gemm(x, 128, pre_w, 128, pre_b, nullptr, emb, 512, n, 128, 128, 0, 0);

    const int gather_grid = (int)(((long long)n * 64 + 255) / 256);
    for (int l = 0; l < 4; ++l) {
        int K = 128 * (l + 1);
        // g = dinv * (emb[:, :K] @ conv_w[l])
        gemm(emb, 512, conv_w[l], 128, nullptr, dinv, g, 128, n, K, 128, 0, 0);
        // h_{l+1} = relu(dinv*(gather(g)+g)+b)
        float* out = (l < 3) ? (emb + (size_t)128 * (l + 1)) : h4;
        int ldo = (l < 3) ? 512 : 128;
        gcn_gather<<<gather_grid, 256, 0, stream>>>(rp, csr, g, dinv, conv_b[l], out, ldo, n);
    }

    // post_mp
    // h1 = LeakyReLU( emb[:, :512]@W1[:512] + h4@W1[512:] + b1 ), two passes
    gemm(emb, 512, post_w1, 128, nullptr, nullptr, h1, 128, n, 512, 128, 0, 0);
    gemm(h4, 128, post_w1 + (size_t)512 * 128, 128, post_b1, nullptr, h1, 128, n, 128, 128, 2, 1);
    // h2 = relu(h1@W2 + b2)
    gemm(h1, 128, post_w2, 128, post_b2, nullptr, h2, 128, n, 128, 128, 1, 0);
    // h3 = relu(h2@W3 + b3)   N=256
    gemm(h2, 128, post_w3, 256, post_b3, nullptr, h3, 256, n, 128, 256, 1, 0);
    // out = h3@W4 + b4
    gemm(h3, 256, post_w4, 128, post_b4, nullptr, (float*)d_out, 128, n, 256, 128, 0, 0);
}

// Round 4
// 1025.095 us; speedup vs baseline: 11.6613x; 1.7967x over previous
//
#include <hip/hip_runtime.h>

// ---------------------------------------------------------------------------
// GeneralGNN: 4-layer GCN (skip='all') + MLP head.
// Round 3: all GEMMs -> bf16 MFMA (16x16x32, f32 accum); gather reads bf16.
//   g = dinv * (emb @ W)         (GEMM epilogue rowscale, bf16 out)
//   h = relu(dinv*(gather+self)+b)  (fused gather, bf16 out)
// ws: emb n*512 bf16 | g n*128 bf16 | h4 n*128 bf16 | xb n*128 bf16 |
//     dinv f32 n | rp n | csr E | wt-pool bf16          (~187 MB)
// ---------------------------------------------------------------------------

typedef __bf16 bf16;
typedef __attribute__((ext_vector_type(8))) __bf16 bf16x8;
typedef __attribute__((ext_vector_type(4))) __bf16 bf16x4;
typedef __attribute__((ext_vector_type(4))) float f32x4;

// ---------------- CSR build ----------------
__global__ __launch_bounds__(256) void zero_int(int* p, int n) {
    int i = blockIdx.x * 256 + threadIdx.x;
    if (i < n) p[i] = 0;
}

__global__ __launch_bounds__(256) void hist_dst(const int* __restrict__ ei, int* cnt, int E) {
    int e = blockIdx.x * 256 + threadIdx.x;
    if (e < E) atomicAdd(&cnt[ei[E + e]], 1);
}

__global__ __launch_bounds__(1024) void scan_excl(const int* __restrict__ cnt, int* __restrict__ rp, int n) {
    __shared__ int sums[1024];
    const int t = threadIdx.x;
    const int chunk = (n + 1023) / 1024;
    const int lo = t * chunk;
    const int hi = min(lo + chunk, n);
    int s = 0;
    for (int i = lo; i < hi; ++i) s += cnt[i];
    sums[t] = s;
    __syncthreads();
    for (int off = 1; off < 1024; off <<= 1) {
        int v = (t >= off) ? sums[t - off] : 0;
        __syncthreads();
        sums[t] += v;
        __syncthreads();
    }
    int base = (t == 0) ? 0 : sums[t - 1];
    for (int i = lo; i < hi; ++i) { rp[i] = base; base += cnt[i]; }
}

__global__ __launch_bounds__(256) void csr_fill(const int* __restrict__ ei, int* rp, int* csr, int E) {
    int e = blockIdx.x * 256 + threadIdx.x;
    if (e < E) {
        int pos = atomicAdd(&rp[ei[E + e]], 1);
        csr[pos] = ei[e];
    }
}

__global__ __launch_bounds__(256) void make_dinv(const int* __restrict__ rp, float* dinv, int n) {
    int i = blockIdx.x * 256 + threadIdx.x;
    if (i < n) {
        int start = i ? rp[i - 1] : 0;
        dinv[i] = rsqrtf((float)(rp[i] - start + 1));
    }
}

// ---------------- casts ----------------
__global__ __launch_bounds__(256) void cast_f32_bf16(const float* __restrict__ in,
                                                     bf16* __restrict__ out, long long n4) {
    long long i = (long long)blockIdx.x * 256 + threadIdx.x;
    if (i < n4) {
        float4 v = ((const float4*)in)[i];
        bf16x4 o = {(bf16)v.x, (bf16)v.y, (bf16)v.z, (bf16)v.w};
        ((bf16x4*)out)[i] = o;
    }
}

// wt[N][K] = (bf16) w[K][N]
__global__ __launch_bounds__(256) void transpose_w(const float* __restrict__ w,
                                                   bf16* __restrict__ wt, int K, int N) {
    int idx = blockIdx.x * 256 + threadIdx.x;
    if (idx < K * N) {
        int k = idx / N, nn = idx % N;
        wt[(size_t)nn * K + k] = (bf16)w[idx];
    }
}

// ---------------- bf16 MFMA GEMM ----------------
// C[M,N] = act( rowscale * ([A1|A2][M,Ktot] @ WT^T) + bias )
// A1 covers k<K1 (ld lda1), A2 covers k>=K1 (ld lda2). WT is [Ntot][Ktot] bf16.
// Tile 128x128, BK=64, 4 waves (2x2), reg-staged LDS, XOR-swizzled.
__global__ __launch_bounds__(256) void gemm_bf16(
    const bf16* __restrict__ A1, int lda1, int K1,
    const bf16* __restrict__ A2, int lda2,
    const bf16* __restrict__ WT,
    const float* __restrict__ bias,
    const float* __restrict__ rowscale,
    void* __restrict__ Cout, int ldc, int M, int Ktot,
    int act, int outf32)
{
    __shared__ bf16 Als[128 * 64];
    __shared__ bf16 Bls[128 * 64];

    const int t = threadIdx.x;
    const int lane = t & 63;
    const int wid = t >> 6;
    const int wm = wid >> 1, wn = wid & 1;
    const int row0 = blockIdx.x * 128;
    const int col0 = blockIdx.y * 128;
    const int nt = Ktot >> 6;

    f32x4 acc[4][4];
#pragma unroll
    for (int mf = 0; mf < 4; ++mf)
#pragma unroll
        for (int nf = 0; nf < 4; ++nf) {
            f32x4 z = {0.f, 0.f, 0.f, 0.f};
            acc[mf][nf] = z;
        }

    // staging chunk coords: ch = t + i*256 -> row=ch>>3 (0..127), chunk=ch&7
    int sr[4], sc[4];
#pragma unroll
    for (int i = 0; i < 4; ++i) { int ch = t + i * 256; sr[i] = ch >> 3; sc[i] = ch & 7; }

    bf16x8 ra[4], rb[4];

    auto gload = [&](int k0) {
        const bf16* Ap; int lda_, kk;
        if (k0 < K1) { Ap = A1; lda_ = lda1; kk = k0; }
        else         { Ap = A2; lda_ = lda2; kk = k0 - K1; }
#pragma unroll
        for (int i = 0; i < 4; ++i) {
            int grow = row0 + sr[i]; if (grow >= M) grow = M - 1;
            ra[i] = *(const bf16x8*)&Ap[(size_t)grow * lda_ + kk + sc[i] * 8];
            rb[i] = *(const bf16x8*)&WT[(size_t)(col0 + sr[i]) * Ktot + k0 + sc[i] * 8];
        }
    };

    gload(0);

    for (int kt = 0; kt < nt; ++kt) {
        __syncthreads();   // all waves done reading previous tile
#pragma unroll
        for (int i = 0; i < 4; ++i) {
            int boff = sr[i] * 128 + ((sc[i] ^ (sr[i] & 7)) << 4);
            *(bf16x8*)((char*)Als + boff) = ra[i];
            *(bf16x8*)((char*)Bls + boff) = rb[i];
        }
        __syncthreads();
        if (kt + 1 < nt) gload((kt + 1) * 64);   // issue-early, overlaps MFMA

#pragma unroll
        for (int ks = 0; ks < 2; ++ks) {
            bf16x8 af[4], bfr[4];
#pragma unroll
            for (int mf = 0; mf < 4; ++mf) {
                int r = wm * 64 + mf * 16 + (lane & 15);
                int ch = (ks * 4 + (lane >> 4)) ^ (r & 7);
                af[mf] = *(const bf16x8*)((const char*)Als + r * 128 + ch * 16);
            }
#pragma unroll
            for (int nf = 0; nf < 4; ++nf) {
                int r = wn * 64 + nf * 16 + (lane & 15);
                int ch = (ks * 4 + (lane >> 4)) ^ (r & 7);
                bfr[nf] = *(const bf16x8*)((const char*)Bls + r * 128 + ch * 16);
            }
#pragma unroll
            for (int mf = 0; mf < 4; ++mf)
#pragma unroll
                for (int nf = 0; nf < 4; ++nf)
                    acc[mf][nf] = __builtin_amdgcn_mfma_f32_16x16x32_bf16(
                        af[mf], bfr[nf], acc[mf][nf], 0, 0, 0);
        }
    }

    // epilogue: D row = (lane>>4)*4+i, col = lane&15 within each 16x16 frag
#pragma unroll
    for (int mf = 0; mf < 4; ++mf) {
        int rbase = row0 + wm * 64 + mf * 16 + (lane >> 4) * 4;
#pragma unroll
        for (int nf = 0; nf < 4; ++nf) {
            int gcol = col0 + wn * 64 + nf * 16 + (lane & 15);
            float bv = bias ? bias[gcol] : 0.f;
#pragma unroll
            for (int i = 0; i < 4; ++i) {
                int grow = rbase + i;
                if (grow >= M) continue;
                float v = acc[mf][nf][i];
                if (rowscale) v *= rowscale[grow];
                v += bv;
                if (act == 1) v = fmaxf(v, 0.f);
                else if (act == 2) v = v > 0.f ? v : 0.1f * v;
                if (outf32) ((float*)Cout)[(size_t)grow * ldc + gcol] = v;
                else        ((bf16*)Cout)[(size_t)grow * ldc + gcol] = (bf16)v;
            }
        }
    }
}

// ---------------- fused gather ----------------
// wave per node; 4 edges in flight (grp=lane>>4), 16B/lane; f32 accum.
// out[i,:] = relu( dinv[i] * (sum g[src] + g[i]) + b )   (bf16 out)
__global__ __launch_bounds__(256) void gcn_gather(
    const int* __restrict__ rp, const int* __restrict__ csr,
    const bf16* __restrict__ g, const float* __restrict__ dinv,
    const float* __restrict__ b,
    bf16* __restrict__ out, int ldo, int n)
{
    const int node = (int)(((long long)blockIdx.x * 256 + threadIdx.x) >> 6);
    if (node >= n) return;
    const int lane = threadIdx.x & 63;
    const int grp = lane >> 4;
    const int cc = lane & 15;
    const int start = node ? rp[node - 1] : 0;
    const int end = rp[node];

    float acc[8];
#pragma unroll
    for (int j = 0; j < 8; ++j) acc[j] = 0.f;

    for (int j0 = start + grp; j0 < end; j0 += 4) {
        int src = csr[j0];
        bf16x8 v = *(const bf16x8*)&g[(size_t)src * 128 + cc * 8];
#pragma unroll
        for (int j = 0; j < 8; ++j) acc[j] += (float)v[j];
    }
#pragma unroll
    for (int j = 0; j < 8; ++j) {
        acc[j] += __shfl_xor(acc[j], 16, 64);
        acc[j] += __shfl_xor(acc[j], 32, 64);
    }
    if (grp == 0) {
        bf16x8 sv = *(const bf16x8*)&g[(size_t)node * 128 + cc * 8];
        float s = dinv[node];
        bf16x8 o;
#pragma unroll
        for (int j = 0; j < 8; ++j) {
            float v = fmaf(s, acc[j] + (float)sv[j], b[cc * 8 + j]);
            o[j] = (bf16)fmaxf(v, 0.f);
        }
        *(bf16x8*)&out[(size_t)node * ldo + cc * 8] = o;
    }
}

// ---------------- launcher ----------------
extern "C" void kernel_launch(void* const* d_in, const int* in_sizes, int n_in,
                              void* d_out, int out_size, void* d_ws, size_t ws_size,
                              hipStream_t stream) {
    const float* x      = (const float*)d_in[0];
    const int*   ei     = (const int*)d_in[1];
    const float* pre_w  = (const float*)d_in[2];
    const float* pre_b  = (const float*)d_in[3];
    const float* conv_w[4] = {(const float*)d_in[4], (const float*)d_in[6],
                              (const float*)d_in[8], (const float*)d_in[10]};
    const float* conv_b[4] = {(const float*)d_in[5], (const float*)d_in[7],
                              (const float*)d_in[9], (const float*)d_in[11]};
    const float* post_w1 = (const float*)d_in[12];
    const float* post_b1 = (const float*)d_in[13];
    const float* post_w2 = (const float*)d_in[14];
    const float* post_b2 = (const float*)d_in[15];
    const float* post_w3 = (const float*)d_in[16];
    const float* post_b3 = (const float*)d_in[17];
    const float* post_w4 = (const float*)d_in[18];
    const float* post_b4 = (const float*)d_in[19];

    const int n = in_sizes[0] / 128;    // 100000
    const int E = in_sizes[1] / 2;      // 1600000

    // ws layout (bytes)
    size_t off = 0;
    bf16* emb  = (bf16*)((char*)d_ws + off); off += (size_t)n * 512 * 2;
    bf16* g    = (bf16*)((char*)d_ws + off); off += (size_t)n * 128 * 2;
    bf16* h4   = (bf16*)((char*)d_ws + off); off += (size_t)n * 128 * 2;
    bf16* xb   = (bf16*)((char*)d_ws + off); off += (size_t)n * 128 * 2;
    float* dinv = (float*)((char*)d_ws + off); off += (size_t)n * 4;
    int*   rp   = (int*)((char*)d_ws + off); off += (size_t)n * 4;
    int*   csr  = (int*)((char*)d_ws + off); off += (size_t)E * 4;
    bf16*  wt   = (bf16*)((char*)d_ws + off); off += (size_t)344064 * 2;
    if (ws_size < off) return;  // diagnostic early-out

    int* cnt = (int*)dinv;      // overlay during CSR build
    bf16* h1 = g;               // post overlays on dead buffers
    bf16* h2 = xb;
    bf16* h3 = emb;

    // weight-pool offsets (elements)
    bf16* pre_wt  = wt;            // [128][128]
    bf16* c_wt0   = wt + 16384;    // [128][128]
    bf16* c_wt1   = wt + 32768;    // [128][256]
    bf16* c_wt2   = wt + 65536;    // [128][384]
    bf16* c_wt3   = wt + 114688;   // [128][512]
    bf16* p1_wt   = wt + 180224;   // [128][640]
    bf16* p2_wt   = wt + 262144;   // [128][128]
    bf16* p3_wt   = wt + 278528;   // [256][128]
    bf16* p4_wt   = wt + 311296;   // [128][256]
    bf16* c_wt[4] = {c_wt0, c_wt1, c_wt2, c_wt3};

    // ---- CSR build ----
    zero_int<<<(n + 255) / 256, 256, 0, stream>>>(cnt, n);
    hist_dst<<<(E + 255) / 256, 256, 0, stream>>>(ei, cnt, E);
    scan_excl<<<1, 1024, 0, stream>>>(cnt, rp, n);
    csr_fill<<<(E + 255) / 256, 256, 0, stream>>>(ei, rp, csr, E);
    make_dinv<<<(n + 255) / 256, 256, 0, stream>>>(rp, dinv, n);

    // ---- casts ----
    cast_f32_bf16<<<(int)(((long long)n * 32 + 255) / 256), 256, 0, stream>>>(x, xb, (long long)n * 32);
    auto tw = [&](const float* w, bf16* dst, int K, int N) {
        transpose_w<<<(K * N + 255) / 256, 256, 0, stream>>>(w, dst, K, N);
    };
    tw(pre_w, pre_wt, 128, 128);
    for (int l = 0; l < 4; ++l) tw(conv_w[l], c_wt[l], 128 * (l + 1), 128);
    tw(post_w1, p1_wt, 640, 128);
    tw(post_w2, p2_wt, 128, 128);
    tw(post_w3, p3_wt, 128, 256);
    tw(post_w4, p4_wt, 256, 128);

    const int gx = (n + 127) / 128;
    auto gemm = [&](const bf16* A1, int lda1, int K1, const bf16* A2, int lda2,
                    const bf16* WT, const float* bias, const float* rs,
                    void* C, int ldc, int Ktot, int N, int act, int outf32) {
        dim3 grid(gx, N / 128);
        gemm_bf16<<<grid, 256, 0, stream>>>(A1, lda1, K1, A2, lda2, WT, bias, rs,
                                            C, ldc, n, Ktot, act, outf32);
    };

    // pre_mp: emb[:, 0:128] = x @ pre_w + pre_b
    gemm(xb, 128, 128, xb, 128, pre_wt, pre_b, nullptr, emb, 512, 128, 128, 0, 0);

    const int ggrid = (int)(((long long)n * 64 + 255) / 256);
    for (int l = 0; l < 4; ++l) {
        int K = 128 * (l + 1);
        gemm(emb, 512, K, emb, 512, c_wt[l], nullptr, dinv, g, 128, K, 128, 0, 0);
        bf16* out = (l < 3) ? (emb + (size_t)128 * (l + 1)) : h4;
        int ldo = (l < 3) ? 512 : 128;
        gcn_gather<<<ggrid, 256, 0, stream>>>(rp, csr, g, dinv, conv_b[l], out, ldo, n);
    }

    // post_mp
    gemm(emb, 512, 512, h4, 128, p1_wt, post_b1, nullptr, h1, 128, 640, 128, 2, 0);
    gemm(h1, 128, 128, h1, 128, p2_wt, post_b2, nullptr, h2, 128, 128, 128, 1, 0);
    gemm(h2, 128, 128, h2, 128, p3_wt, post_b3, nullptr, h3, 256, 128, 256, 1, 0);
    gemm(h3, 256, 256, h3, 256, p4_wt, post_b4, nullptr, d_out, 128, 256, 128, 0, 1);
}

// Round 5
// 872.019 us; speedup vs baseline: 13.7083x; 1.1755x over previous
//
#include <hip/hip_runtime.h>

// ---------------------------------------------------------------------------
// GeneralGNN: 4-layer GCN (skip='all') + MLP head.
// Round 4: parallel CSR scan (was 162us single-block) + global_load_lds GEMM
// staging with pre-swizzled global source (linear LDS dest, T2-swizzled reads).
// ---------------------------------------------------------------------------

typedef __bf16 bf16;
typedef __attribute__((ext_vector_type(8))) __bf16 bf16x8;
typedef __attribute__((ext_vector_type(4))) __bf16 bf16x4;
typedef __attribute__((ext_vector_type(4))) float f32x4;

// ---------------- CSR build ----------------
__global__ __launch_bounds__(256) void zero_int(int* p, int n) {
    int i = blockIdx.x * 256 + threadIdx.x;
    if (i < n) p[i] = 0;
}

__global__ __launch_bounds__(256) void hist_dst(const int* __restrict__ ei, int* cnt, int E) {
    int e = blockIdx.x * 256 + threadIdx.x;
    if (e < E) atomicAdd(&cnt[ei[E + e]], 1);
}

// level 1: per-block (1024 elems) exclusive scan + block sums.
// Also emits dinv[i] = rsqrt(cnt[i]+1) (cnt overlays dinv; read-before-write).
__global__ __launch_bounds__(256) void scan1(const int* __restrict__ cnt,
                                             int* __restrict__ rp,
                                             float* __restrict__ dinv,
                                             int* __restrict__ bsum, int n) {
    __shared__ int sums[256];
    const int t = threadIdx.x;
    const int base = blockIdx.x * 1024 + t * 4;
    int4 v = make_int4(0, 0, 0, 0);
    if (base < n) v = *(const int4*)&cnt[base];          // n % 4 == 0
    int s = v.x + v.y + v.z + v.w;
    sums[t] = s;
    __syncthreads();
#pragma unroll
    for (int off = 1; off < 256; off <<= 1) {
        int u = (t >= off) ? sums[t - off] : 0;
        __syncthreads();
        sums[t] += u;
        __syncthreads();
    }
    int excl = sums[t] - s;
    if (base < n) {
        int4 r;
        r.x = excl;
        r.y = r.x + v.x;
        r.z = r.y + v.y;
        r.w = r.z + v.z;
        *(int4*)&rp[base] = r;
        float4 dv;
        dv.x = rsqrtf((float)(v.x + 1));
        dv.y = rsqrtf((float)(v.y + 1));
        dv.z = rsqrtf((float)(v.z + 1));
        dv.w = rsqrtf((float)(v.w + 1));
        *(float4*)&dinv[base] = dv;
    }
    if (t == 255) bsum[blockIdx.x] = sums[255];
}

// level 2: single block, exclusive scan of nb block sums (nb <= 128)
__global__ __launch_bounds__(128) void scan2(int* __restrict__ bsum, int nb) {
    __shared__ int sums[128];
    const int t = threadIdx.x;
    int s = (t < nb) ? bsum[t] : 0;
    sums[t] = s;
    __syncthreads();
#pragma unroll
    for (int off = 1; off < 128; off <<= 1) {
        int u = (t >= off) ? sums[t - off] : 0;
        __syncthreads();
        sums[t] += u;
        __syncthreads();
    }
    if (t < nb) bsum[t] = sums[t] - s;   // exclusive
}

// level 3: add block offsets
__global__ __launch_bounds__(256) void scan3(int* __restrict__ rp,
                                             const int* __restrict__ bsum, int n) {
    const int base = blockIdx.x * 1024 + threadIdx.x * 4;
    if (base < n) {
        int o = bsum[blockIdx.x];
        int4 r = *(int4*)&rp[base];
        r.x += o; r.y += o; r.z += o; r.w += o;
        *(int4*)&rp[base] = r;
    }
}

// fill CSR using rp as running cursor; after this rp[i] == end of row i.
__global__ __launch_bounds__(256) void csr_fill(const int* __restrict__ ei, int* rp, int* csr, int E) {
    int e = blockIdx.x * 256 + threadIdx.x;
    if (e < E) {
        int pos = atomicAdd(&rp[ei[E + e]], 1);
        csr[pos] = ei[e];
    }
}

// ---------------- casts ----------------
__global__ __launch_bounds__(256) void cast_f32_bf16(const float* __restrict__ in,
                                                     bf16* __restrict__ out, long long n4) {
    long long i = (long long)blockIdx.x * 256 + threadIdx.x;
    if (i < n4) {
        float4 v = ((const float4*)in)[i];
        bf16x4 o = {(bf16)v.x, (bf16)v.y, (bf16)v.z, (bf16)v.w};
        ((bf16x4*)out)[i] = o;
    }
}

// wt[N][K] = (bf16) w[K][N]
__global__ __launch_bounds__(256) void transpose_w(const float* __restrict__ w,
                                                   bf16* __restrict__ wt, int K, int N) {
    int idx = blockIdx.x * 256 + threadIdx.x;
    if (idx < K * N) {
        int k = idx / N, nn = idx % N;
        wt[(size_t)nn * K + k] = (bf16)w[idx];
    }
}

// ---------------- bf16 MFMA GEMM ----------------
// C[M,N] = act( rowscale * ([A1|A2][M,Ktot] @ WT^T) + bias )
// Tile 128x128, BK=64, 4 waves (2x2). Staging via global_load_lds width=16:
// linear LDS dest, global source pre-swizzled by chunk ^= (row&7); fragment
// reads apply the same XOR (bank-conflict-free, rule #21 both-sides pattern).
__global__ __launch_bounds__(256) void gemm_bf16(
    const bf16* __restrict__ A1, int lda1, int K1,
    const bf16* __restrict__ A2, int lda2,
    const bf16* __restrict__ WT,
    const float* __restrict__ bias,
    const float* __restrict__ rowscale,
    void* __restrict__ Cout, int ldc, int M, int Ktot,
    int act, int outf32)
{
    __shared__ bf16 Als[128 * 64];
    __shared__ bf16 Bls[128 * 64];

    const int t = threadIdx.x;
    const int lane = t & 63;
    const int wid = t >> 6;
    const int wm = wid >> 1, wn = wid & 1;
    const int row0 = blockIdx.x * 128;
    const int col0 = blockIdx.y * 128;
    const int nt = Ktot >> 6;

    f32x4 acc[4][4];
#pragma unroll
    for (int mf = 0; mf < 4; ++mf)
#pragma unroll
        for (int nf = 0; nf < 4; ++nf) {
            f32x4 z = {0.f, 0.f, 0.f, 0.f};
            acc[mf][nf] = z;
        }

    // per-lane staging coords: ch = wid*64 + i*256 + lane; row=ch>>3, chunk=ch&7
    // global source uses swizzled chunk cs = c ^ (row&7); LDS dest is linear.
    int srow[4], scs[4];
#pragma unroll
    for (int i = 0; i < 4; ++i) {
        int ch = wid * 64 + i * 256 + lane;
        int row = ch >> 3, c = ch & 7;
        srow[i] = row;
        scs[i] = (c ^ (row & 7)) * 8;
    }

    for (int kt = 0; kt < nt; ++kt) {
        const int k0 = kt * 64;
        const bf16* Ap; int lda_, kk;
        if (k0 < K1) { Ap = A1; lda_ = lda1; kk = k0; }
        else         { Ap = A2; lda_ = lda2; kk = k0 - K1; }

        __syncthreads();   // all waves done reading LDS from previous step
#pragma unroll
        for (int i = 0; i < 4; ++i) {
            int grow = row0 + srow[i]; if (grow >= M) grow = M - 1;
            const bf16* ga = &Ap[(size_t)grow * lda_ + kk + scs[i]];
            const bf16* gb = &WT[(size_t)(col0 + srow[i]) * Ktot + k0 + scs[i]];
            bf16* la = &Als[(size_t)(wid * 64 + i * 256) * 8];   // wave-uniform base
            bf16* lb = &Bls[(size_t)(wid * 64 + i * 256) * 8];
            __builtin_amdgcn_global_load_lds(
                (const __attribute__((address_space(1))) void*)ga,
                (__attribute__((address_space(3))) void*)la, 16, 0, 0);
            __builtin_amdgcn_global_load_lds(
                (const __attribute__((address_space(1))) void*)gb,
                (__attribute__((address_space(3))) void*)lb, 16, 0, 0);
        }
        asm volatile("s_waitcnt vmcnt(0)" ::: "memory");
        __syncthreads();

#pragma unroll
        for (int ks = 0; ks < 2; ++ks) {
            bf16x8 af[4], bfr[4];
#pragma unroll
            for (int mf = 0; mf < 4; ++mf) {
                int r = wm * 64 + mf * 16 + (lane & 15);
                int ch = (ks * 4 + (lane >> 4)) ^ (r & 7);
                af[mf] = *(const bf16x8*)((const char*)Als + r * 128 + ch * 16);
            }
#pragma unroll
            for (int nf = 0; nf < 4; ++nf) {
                int r = wn * 64 + nf * 16 + (lane & 15);
                int ch = (ks * 4 + (lane >> 4)) ^ (r & 7);
                bfr[nf] = *(const bf16x8*)((const char*)Bls + r * 128 + ch * 16);
            }
#pragma unroll
            for (int mf = 0; mf < 4; ++mf)
#pragma unroll
                for (int nf = 0; nf < 4; ++nf)
                    acc[mf][nf] = __builtin_amdgcn_mfma_f32_16x16x32_bf16(
                        af[mf], bfr[nf], acc[mf][nf], 0, 0, 0);
        }
    }

    // epilogue: D row = (lane>>4)*4+i, col = lane&15 within each 16x16 frag
#pragma unroll
    for (int mf = 0; mf < 4; ++mf) {
        int rbase = row0 + wm * 64 + mf * 16 + (lane >> 4) * 4;
#pragma unroll
        for (int nf = 0; nf < 4; ++nf) {
            int gcol = col0 + wn * 64 + nf * 16 + (lane & 15);
            float bv = bias ? bias[gcol] : 0.f;
#pragma unroll
            for (int i = 0; i < 4; ++i) {
                int grow = rbase + i;
                if (grow >= M) continue;
                float v = acc[mf][nf][i];
                if (rowscale) v *= rowscale[grow];
                v += bv;
                if (act == 1) v = fmaxf(v, 0.f);
                else if (act == 2) v = v > 0.f ? v : 0.1f * v;
                if (outf32) ((float*)Cout)[(size_t)grow * ldc + gcol] = v;
                else        ((bf16*)Cout)[(size_t)grow * ldc + gcol] = (bf16)v;
            }
        }
    }
}

// ---------------- fused gather ----------------
// wave per node; 4 edges in flight (grp=lane>>4), 16B/lane; f32 accum.
__global__ __launch_bounds__(256) void gcn_gather(
    const int* __restrict__ rp, const int* __restrict__ csr,
    const bf16* __restrict__ g, const float* __restrict__ dinv,
    const float* __restrict__ b,
    bf16* __restrict__ out, int ldo, int n)
{
    const int node = (int)(((long long)blockIdx.x * 256 + threadIdx.x) >> 6);
    if (node >= n) return;
    const int lane = threadIdx.x & 63;
    const int grp = lane >> 4;
    const int cc = lane & 15;
    const int start = node ? rp[node - 1] : 0;
    const int end = rp[node];

    float acc[8];
#pragma unroll
    for (int j = 0; j < 8; ++j) acc[j] = 0.f;

    for (int j0 = start + grp; j0 < end; j0 += 4) {
        int src = csr[j0];
        bf16x8 v = *(const bf16x8*)&g[(size_t)src * 128 + cc * 8];
#pragma unroll
        for (int j = 0; j < 8; ++j) acc[j] += (float)v[j];
    }
#pragma unroll
    for (int j = 0; j < 8; ++j) {
        acc[j] += __shfl_xor(acc[j], 16, 64);
        acc[j] += __shfl_xor(acc[j], 32, 64);
    }
    if (grp == 0) {
        bf16x8 sv = *(const bf16x8*)&g[(size_t)node * 128 + cc * 8];
        float s = dinv[node];
        bf16x8 o;
#pragma unroll
        for (int j = 0; j < 8; ++j) {
            float v = fmaf(s, acc[j] + (float)sv[j], b[cc * 8 + j]);
            o[j] = (bf16)fmaxf(v, 0.f);
        }
        *(bf16x8*)&out[(size_t)node * ldo + cc * 8] = o;
    }
}

// ---------------- launcher ----------------
extern "C" void kernel_launch(void* const* d_in, const int* in_sizes, int n_in,
                              void* d_out, int out_size, void* d_ws, size_t ws_size,
                              hipStream_t stream) {
    const float* x      = (const float*)d_in[0];
    const int*   ei     = (const int*)d_in[1];
    const float* pre_w  = (const float*)d_in[2];
    const float* pre_b  = (const float*)d_in[3];
    const float* conv_w[4] = {(const float*)d_in[4], (const float*)d_in[6],
                              (const float*)d_in[8], (const float*)d_in[10]};
    const float* conv_b[4] = {(const float*)d_in[5], (const float*)d_in[7],
                              (const float*)d_in[9], (const float*)d_in[11]};
    const float* post_w1 = (const float*)d_in[12];
    const float* post_b1 = (const float*)d_in[13];
    const float* post_w2 = (const float*)d_in[14];
    const float* post_b2 = (const float*)d_in[15];
    const float* post_w3 = (const float*)d_in[16];
    const float* post_b3 = (const float*)d_in[17];
    const float* post_w4 = (const float*)d_in[18];
    const float* post_b4 = (const float*)d_in[19];

    const int n = in_sizes[0] / 128;    // 100000
    const int E = in_sizes[1] / 2;      // 1600000
    const int nb = (n + 1023) / 1024;   // 98 scan blocks

    // ws layout (bytes)
    size_t off = 0;
    bf16* emb  = (bf16*)((char*)d_ws + off); off += (size_t)n * 512 * 2;
    bf16* g    = (bf16*)((char*)d_ws + off); off += (size_t)n * 128 * 2;
    bf16* h4   = (bf16*)((char*)d_ws + off); off += (size_t)n * 128 * 2;
    bf16* xb   = (bf16*)((char*)d_ws + off); off += (size_t)n * 128 * 2;
    float* dinv = (float*)((char*)d_ws + off); off += (size_t)n * 4;
    int*   rp   = (int*)((char*)d_ws + off); off += (size_t)n * 4;
    int*   csr  = (int*)((char*)d_ws + off); off += (size_t)E * 4;
    bf16*  wt   = (bf16*)((char*)d_ws + off); off += (size_t)344064 * 2;
    int*   bsum = (int*)((char*)d_ws + off); off += 128 * 4;
    if (ws_size < off) return;  // diagnostic early-out

    int* cnt = (int*)dinv;      // overlay during CSR build
    bf16* h1 = g;               // post overlays on dead buffers
    bf16* h2 = xb;
    bf16* h3 = emb;

    // weight-pool offsets (elements)
    bf16* pre_wt  = wt;            // [128][128]
    bf16* c_wt0   = wt + 16384;
    bf16* c_wt1   = wt + 32768;
    bf16* c_wt2   = wt + 65536;
    bf16* c_wt3   = wt + 114688;
    bf16* p1_wt   = wt + 180224;   // [128][640]
    bf16* p2_wt   = wt + 262144;
    bf16* p3_wt   = wt + 278528;   // [256][128]
    bf16* p4_wt   = wt + 311296;   // [128][256]
    bf16* c_wt[4] = {c_wt0, c_wt1, c_wt2, c_wt3};

    // ---- CSR build ----
    zero_int<<<(n + 255) / 256, 256, 0, stream>>>(cnt, n);
    hist_dst<<<(E + 255) / 256, 256, 0, stream>>>(ei, cnt, E);
    scan1<<<nb, 256, 0, stream>>>(cnt, rp, dinv, bsum, n);   // also fills dinv
    scan2<<<1, 128, 0, stream>>>(bsum, nb);
    scan3<<<nb, 256, 0, stream>>>(rp, bsum, n);
    csr_fill<<<(E + 255) / 256, 256, 0, stream>>>(ei, rp, csr, E);

    // ---- casts ----
    cast_f32_bf16<<<(int)(((long long)n * 32 + 255) / 256), 256, 0, stream>>>(x, xb, (long long)n * 32);
    auto tw = [&](const float* w, bf16* dst, int K, int N) {
        transpose_w<<<(K * N + 255) / 256, 256, 0, stream>>>(w, dst, K, N);
    };
    tw(pre_w, pre_wt, 128, 128);
    for (int l = 0; l < 4; ++l) tw(conv_w[l], c_wt[l], 128 * (l + 1), 128);
    tw(post_w1, p1_wt, 640, 128);
    tw(post_w2, p2_wt, 128, 128);
    tw(post_w3, p3_wt, 128, 256);
    tw(post_w4, p4_wt, 256, 128);

    const int gx = (n + 127) / 128;
    auto gemm = [&](const bf16* A1, int lda1, int K1, const bf16* A2, int lda2,
                    const bf16* WT, const float* bias, const float* rs,
                    void* C, int ldc, int Ktot, int N, int act, int outf32) {
        dim3 grid(gx, N / 128);
        gemm_bf16<<<grid, 256, 0, stream>>>(A1, lda1, K1, A2, lda2, WT, bias, rs,
                                            C, ldc, n, Ktot, act, outf32);
    };

    // pre_mp
    gemm(xb, 128, 128, xb, 128, pre_wt, pre_b, nullptr, emb, 512, 128, 128, 0, 0);

    const int ggrid = (int)(((long long)n * 64 + 255) / 256);
    for (int l = 0; l < 4; ++l) {
        int K = 128 * (l + 1);
        gemm(emb, 512, K, emb, 512, c_wt[l], nullptr, dinv, g, 128, K, 128, 0, 0);
        bf16* out = (l < 3) ? (emb + (size_t)128 * (l + 1)) : h4;
        int ldo = (l < 3) ? 512 : 128;
        gcn_gather<<<ggrid, 256, 0, stream>>>(rp, csr, g, dinv, conv_b[l], out, ldo, n);
    }

    // post_mp
    gemm(emb, 512, 512, h4, 128, p1_wt, post_b1, nullptr, h1, 128, 640, 128, 2, 0);
    gemm(h1, 128, 128, h1, 128, p2_wt, post_b2, nullptr, h2, 128, 128, 128, 1, 0);
    gemm(h2, 128, 128, h2, 128, p3_wt, post_b3, nullptr, h3, 256, 128, 256, 1, 0);
    gemm(h3, 256, 256, h3, 256, p4_wt, post_b4, nullptr, d_out, 128, 256, 128, 0, 1);
}

// Round 6
// 812.815 us; speedup vs baseline: 14.7068x; 1.0728x over previous
//
#include <hip/hip_runtime.h>

// ---------------------------------------------------------------------------
// GeneralGNN: 4-layer GCN (skip='all') + MLP head.
// Round 5: rank-split CSR fill (no atomic->store dependency chain; rp stays
// a pristine exclusive scan with rp[n]=E) + 2-edge-per-iter gather ILP.
// ---------------------------------------------------------------------------

typedef __bf16 bf16;
typedef __attribute__((ext_vector_type(8))) __bf16 bf16x8;
typedef __attribute__((ext_vector_type(4))) __bf16 bf16x4;
typedef __attribute__((ext_vector_type(4))) float f32x4;

// ---------------- CSR build ----------------
__global__ __launch_bounds__(256) void zero_int(int* p, int n) {
    int i = blockIdx.x * 256 + threadIdx.x;
    if (i < n) p[i] = 0;
}

// cnt[dst]++ and rank[e] = old count (edge's slot within its row)
__global__ __launch_bounds__(256) void hist_dst(const int* __restrict__ ei,
                                                int* cnt, int* __restrict__ rank, int E) {
    int e = blockIdx.x * 256 + threadIdx.x;
    if (e < E) rank[e] = atomicAdd(&cnt[ei[E + e]], 1);
}

// level 1: per-block (1024 elems) exclusive scan + block sums.
// Also emits dinv[i] = rsqrt(cnt[i]+1) (cnt overlays dinv; read-before-write).
__global__ __launch_bounds__(256) void scan1(const int* __restrict__ cnt,
                                             int* __restrict__ rp,
                                             float* __restrict__ dinv,
                                             int* __restrict__ bsum, int n) {
    __shared__ int sums[256];
    const int t = threadIdx.x;
    const int base = blockIdx.x * 1024 + t * 4;
    int4 v = make_int4(0, 0, 0, 0);
    if (base < n) v = *(const int4*)&cnt[base];          // n % 4 == 0
    int s = v.x + v.y + v.z + v.w;
    sums[t] = s;
    __syncthreads();
#pragma unroll
    for (int off = 1; off < 256; off <<= 1) {
        int u = (t >= off) ? sums[t - off] : 0;
        __syncthreads();
        sums[t] += u;
        __syncthreads();
    }
    int excl = sums[t] - s;
    if (base < n) {
        int4 r;
        r.x = excl;
        r.y = r.x + v.x;
        r.z = r.y + v.y;
        r.w = r.z + v.z;
        *(int4*)&rp[base] = r;
        float4 dv;
        dv.x = rsqrtf((float)(v.x + 1));
        dv.y = rsqrtf((float)(v.y + 1));
        dv.z = rsqrtf((float)(v.z + 1));
        dv.w = rsqrtf((float)(v.w + 1));
        *(float4*)&dinv[base] = dv;
    }
    if (t == 255) bsum[blockIdx.x] = sums[255];
}

// level 2: single block, exclusive scan of nb block sums (nb <= 128)
__global__ __launch_bounds__(128) void scan2(int* __restrict__ bsum, int nb) {
    __shared__ int sums[128];
    const int t = threadIdx.x;
    int s = (t < nb) ? bsum[t] : 0;
    sums[t] = s;
    __syncthreads();
#pragma unroll
    for (int off = 1; off < 128; off <<= 1) {
        int u = (t >= off) ? sums[t - off] : 0;
        __syncthreads();
        sums[t] += u;
        __syncthreads();
    }
    if (t < nb) bsum[t] = sums[t] - s;   // exclusive
}

// level 3: add block offsets; also writes sentinel rp[n] = E
__global__ __launch_bounds__(256) void scan3(int* __restrict__ rp,
                                             const int* __restrict__ bsum, int n, int E) {
    const int base = blockIdx.x * 1024 + threadIdx.x * 4;
    if (base < n) {
        int o = bsum[blockIdx.x];
        int4 r = *(int4*)&rp[base];
        r.x += o; r.y += o; r.z += o; r.w += o;
        *(int4*)&rp[base] = r;
    }
    if (blockIdx.x == 0 && threadIdx.x == 0) rp[n] = E;
}

// csr[rp[dst] + rank[e]] = src  — no atomics, 4 independent edges per thread
__global__ __launch_bounds__(256) void csr_fill(const int* __restrict__ ei,
                                                const int* __restrict__ rp,
                                                const int* __restrict__ rank,
                                                int* __restrict__ csr, int E) {
    const int T = gridDim.x * 256;
    int e = blockIdx.x * 256 + threadIdx.x;
#pragma unroll 4
    for (int i = 0; i < 4; ++i) {
        if (e < E) csr[rp[ei[E + e]] + rank[e]] = ei[e];
        e += T;
    }
}

// ---------------- casts ----------------
__global__ __launch_bounds__(256) void cast_f32_bf16(const float* __restrict__ in,
                                                     bf16* __restrict__ out, long long n4) {
    long long i = (long long)blockIdx.x * 256 + threadIdx.x;
    if (i < n4) {
        float4 v = ((const float4*)in)[i];
        bf16x4 o = {(bf16)v.x, (bf16)v.y, (bf16)v.z, (bf16)v.w};
        ((bf16x4*)out)[i] = o;
    }
}

// wt[N][K] = (bf16) w[K][N]
__global__ __launch_bounds__(256) void transpose_w(const float* __restrict__ w,
                                                   bf16* __restrict__ wt, int K, int N) {
    int idx = blockIdx.x * 256 + threadIdx.x;
    if (idx < K * N) {
        int k = idx / N, nn = idx % N;
        wt[(size_t)nn * K + k] = (bf16)w[idx];
    }
}

// ---------------- bf16 MFMA GEMM ----------------
// C[M,N] = act( rowscale * ([A1|A2][M,Ktot] @ WT^T) + bias )
// Tile 128x128, BK=64, 4 waves (2x2). global_load_lds width=16 staging:
// linear LDS dest, global source pre-swizzled by chunk ^= (row&7); fragment
// reads apply the same XOR (bank-conflict-free, both-sides pattern).
__global__ __launch_bounds__(256) void gemm_bf16(
    const bf16* __restrict__ A1, int lda1, int K1,
    const bf16* __restrict__ A2, int lda2,
    const bf16* __restrict__ WT,
    const float* __restrict__ bias,
    const float* __restrict__ rowscale,
    void* __restrict__ Cout, int ldc, int M, int Ktot,
    int act, int outf32)
{
    __shared__ bf16 Als[128 * 64];
    __shared__ bf16 Bls[128 * 64];

    const int t = threadIdx.x;
    const int lane = t & 63;
    const int wid = t >> 6;
    const int wm = wid >> 1, wn = wid & 1;
    const int row0 = blockIdx.x * 128;
    const int col0 = blockIdx.y * 128;
    const int nt = Ktot >> 6;

    f32x4 acc[4][4];
#pragma unroll
    for (int mf = 0; mf < 4; ++mf)
#pragma unroll
        for (int nf = 0; nf < 4; ++nf) {
            f32x4 z = {0.f, 0.f, 0.f, 0.f};
            acc[mf][nf] = z;
        }

    int srow[4], scs[4];
#pragma unroll
    for (int i = 0; i < 4; ++i) {
        int ch = wid * 64 + i * 256 + lane;
        int row = ch >> 3, c = ch & 7;
        srow[i] = row;
        scs[i] = (c ^ (row & 7)) * 8;
    }

    for (int kt = 0; kt < nt; ++kt) {
        const int k0 = kt * 64;
        const bf16* Ap; int lda_, kk;
        if (k0 < K1) { Ap = A1; lda_ = lda1; kk = k0; }
        else         { Ap = A2; lda_ = lda2; kk = k0 - K1; }

        __syncthreads();
#pragma unroll
        for (int i = 0; i < 4; ++i) {
            int grow = row0 + srow[i]; if (grow >= M) grow = M - 1;
            const bf16* ga = &Ap[(size_t)grow * lda_ + kk + scs[i]];
            const bf16* gb = &WT[(size_t)(col0 + srow[i]) * Ktot + k0 + scs[i]];
            bf16* la = &Als[(size_t)(wid * 64 + i * 256) * 8];
            bf16* lb = &Bls[(size_t)(wid * 64 + i * 256) * 8];
            __builtin_amdgcn_global_load_lds(
                (const __attribute__((address_space(1))) void*)ga,
                (__attribute__((address_space(3))) void*)la, 16, 0, 0);
            __builtin_amdgcn_global_load_lds(
                (const __attribute__((address_space(1))) void*)gb,
                (__attribute__((address_space(3))) void*)lb, 16, 0, 0);
        }
        asm volatile("s_waitcnt vmcnt(0)" ::: "memory");
        __syncthreads();

#pragma unroll
        for (int ks = 0; ks < 2; ++ks) {
            bf16x8 af[4], bfr[4];
#pragma unroll
            for (int mf = 0; mf < 4; ++mf) {
                int r = wm * 64 + mf * 16 + (lane & 15);
                int ch = (ks * 4 + (lane >> 4)) ^ (r & 7);
                af[mf] = *(const bf16x8*)((const char*)Als + r * 128 + ch * 16);
            }
#pragma unroll
            for (int nf = 0; nf < 4; ++nf) {
                int r = wn * 64 + nf * 16 + (lane & 15);
                int ch = (ks * 4 + (lane >> 4)) ^ (r & 7);
                bfr[nf] = *(const bf16x8*)((const char*)Bls + r * 128 + ch * 16);
            }
#pragma unroll
            for (int mf = 0; mf < 4; ++mf)
#pragma unroll
                for (int nf = 0; nf < 4; ++nf)
                    acc[mf][nf] = __builtin_amdgcn_mfma_f32_16x16x32_bf16(
                        af[mf], bfr[nf], acc[mf][nf], 0, 0, 0);
        }
    }

#pragma unroll
    for (int mf = 0; mf < 4; ++mf) {
        int rbase = row0 + wm * 64 + mf * 16 + (lane >> 4) * 4;
#pragma unroll
        for (int nf = 0; nf < 4; ++nf) {
            int gcol = col0 + wn * 64 + nf * 16 + (lane & 15);
            float bv = bias ? bias[gcol] : 0.f;
#pragma unroll
            for (int i = 0; i < 4; ++i) {
                int grow = rbase + i;
                if (grow >= M) continue;
                float v = acc[mf][nf][i];
                if (rowscale) v *= rowscale[grow];
                v += bv;
                if (act == 1) v = fmaxf(v, 0.f);
                else if (act == 2) v = v > 0.f ? v : 0.1f * v;
                if (outf32) ((float*)Cout)[(size_t)grow * ldc + gcol] = v;
                else        ((bf16*)Cout)[(size_t)grow * ldc + gcol] = (bf16)v;
            }
        }
    }
}

// ---------------- fused gather ----------------
// wave per node; 4 groups x 16 lanes; 2 edges per group-iteration (ILP).
__global__ __launch_bounds__(256) void gcn_gather(
    const int* __restrict__ rp, const int* __restrict__ csr,
    const bf16* __restrict__ g, const float* __restrict__ dinv,
    const float* __restrict__ b,
    bf16* __restrict__ out, int ldo, int n)
{
    const int node = (int)(((long long)blockIdx.x * 256 + threadIdx.x) >> 6);
    if (node >= n) return;
    const int lane = threadIdx.x & 63;
    const int grp = lane >> 4;
    const int cc = lane & 15;
    const int start = rp[node];
    const int end = rp[node + 1];

    float acc[8];
#pragma unroll
    for (int j = 0; j < 8; ++j) acc[j] = 0.f;

    int j = start + grp;
    for (; j + 4 < end; j += 8) {
        int s0 = csr[j];
        int s1 = csr[j + 4];
        bf16x8 v0 = *(const bf16x8*)&g[(size_t)s0 * 128 + cc * 8];
        bf16x8 v1 = *(const bf16x8*)&g[(size_t)s1 * 128 + cc * 8];
#pragma unroll
        for (int jj = 0; jj < 8; ++jj) acc[jj] += (float)v0[jj] + (float)v1[jj];
    }
    if (j < end) {
        int s0 = csr[j];
        bf16x8 v0 = *(const bf16x8*)&g[(size_t)s0 * 128 + cc * 8];
#pragma unroll
        for (int jj = 0; jj < 8; ++jj) acc[jj] += (float)v0[jj];
    }
#pragma unroll
    for (int jj = 0; jj < 8; ++jj) {
        acc[jj] += __shfl_xor(acc[jj], 16, 64);
        acc[jj] += __shfl_xor(acc[jj], 32, 64);
    }
    if (grp == 0) {
        bf16x8 sv = *(const bf16x8*)&g[(size_t)node * 128 + cc * 8];
        float s = dinv[node];
        bf16x8 o;
#pragma unroll
        for (int jj = 0; jj < 8; ++jj) {
            float v = fmaf(s, acc[jj] + (float)sv[jj], b[cc * 8 + jj]);
            o[jj] = (bf16)fmaxf(v, 0.f);
        }
        *(bf16x8*)&out[(size_t)node * ldo + cc * 8] = o;
    }
}

// ---------------- launcher ----------------
extern "C" void kernel_launch(void* const* d_in, const int* in_sizes, int n_in,
                              void* d_out, int out_size, void* d_ws, size_t ws_size,
                              hipStream_t stream) {
    const float* x      = (const float*)d_in[0];
    const int*   ei     = (const int*)d_in[1];
    const float* pre_w  = (const float*)d_in[2];
    const float* pre_b  = (const float*)d_in[3];
    const float* conv_w[4] = {(const float*)d_in[4], (const float*)d_in[6],
                              (const float*)d_in[8], (const float*)d_in[10]};
    const float* conv_b[4] = {(const float*)d_in[5], (const float*)d_in[7],
                              (const float*)d_in[9], (const float*)d_in[11]};
    const float* post_w1 = (const float*)d_in[12];
    const float* post_b1 = (const float*)d_in[13];
    const float* post_w2 = (const float*)d_in[14];
    const float* post_b2 = (const float*)d_in[15];
    const float* post_w3 = (const float*)d_in[16];
    const float* post_b3 = (const float*)d_in[17];
    const float* post_w4 = (const float*)d_in[18];
    const float* post_b4 = (const float*)d_in[19];

    const int n = in_sizes[0] / 128;    // 100000
    const int E = in_sizes[1] / 2;      // 1600000
    const int nb = (n + 1023) / 1024;   // 98 scan blocks

    // ws layout (bytes)
    size_t off = 0;
    bf16* emb  = (bf16*)((char*)d_ws + off); off += (size_t)n * 512 * 2;
    bf16* g    = (bf16*)((char*)d_ws + off); off += (size_t)n * 128 * 2;
    bf16* h4   = (bf16*)((char*)d_ws + off); off += (size_t)n * 128 * 2;
    bf16* xb   = (bf16*)((char*)d_ws + off); off += (size_t)n * 128 * 2;
    float* dinv = (float*)((char*)d_ws + off); off += (size_t)n * 4;
    int*   rp   = (int*)((char*)d_ws + off); off += (size_t)(n + 4) * 4;
    int*   csr  = (int*)((char*)d_ws + off); off += (size_t)E * 4;
    int*   rank = (int*)((char*)d_ws + off); off += (size_t)E * 4;
    bf16*  wt   = (bf16*)((char*)d_ws + off); off += (size_t)344064 * 2;
    int*   bsum = (int*)((char*)d_ws + off); off += 128 * 4;
    if (ws_size < off) return;  // diagnostic early-out

    int* cnt = (int*)dinv;      // overlay during CSR build
    bf16* h1 = g;               // post overlays on dead buffers
    bf16* h2 = xb;
    bf16* h3 = emb;

    // weight-pool offsets (elements)
    bf16* pre_wt  = wt;            // [128][128]
    bf16* c_wt0   = wt + 16384;
    bf16* c_wt1   = wt + 32768;
    bf16* c_wt2   = wt + 65536;
    bf16* c_wt3   = wt + 114688;
    bf16* p1_wt   = wt + 180224;   // [128][640]
    bf16* p2_wt   = wt + 262144;
    bf16* p3_wt   = wt + 278528;   // [256][128]
    bf16* p4_wt   = wt + 311296;   // [128][256]
    bf16* c_wt[4] = {c_wt0, c_wt1, c_wt2, c_wt3};

    // ---- CSR build ----
    zero_int<<<(n + 255) / 256, 256, 0, stream>>>(cnt, n);
    hist_dst<<<(E + 255) / 256, 256, 0, stream>>>(ei, cnt, rank, E);
    scan1<<<nb, 256, 0, stream>>>(cnt, rp, dinv, bsum, n);
    scan2<<<1, 128, 0, stream>>>(bsum, nb);
    scan3<<<nb, 256, 0, stream>>>(rp, bsum, n, E);
    csr_fill<<<(E / 4 + 255) / 256, 256, 0, stream>>>(ei, rp, rank, csr, E);

    // ---- casts ----
    cast_f32_bf16<<<(int)(((long long)n * 32 + 255) / 256), 256, 0, stream>>>(x, xb, (long long)n * 32);
    auto tw = [&](const float* w, bf16* dst, int K, int N) {
        transpose_w<<<(K * N + 255) / 256, 256, 0, stream>>>(w, dst, K, N);
    };
    tw(pre_w, pre_wt, 128, 128);
    for (int l = 0; l < 4; ++l) tw(conv_w[l], c_wt[l], 128 * (l + 1), 128);
    tw(post_w1, p1_wt, 640, 128);
    tw(post_w2, p2_wt, 128, 128);
    tw(post_w3, p3_wt, 128, 256);
    tw(post_w4, p4_wt, 256, 128);

    const int gx = (n + 127) / 128;
    auto gemm = [&](const bf16* A1, int lda1, int K1, const bf16* A2, int lda2,
                    const bf16* WT, const float* bias, const float* rs,
                    void* C, int ldc, int Ktot, int N, int act, int outf32) {
        dim3 grid(gx, N / 128);
        gemm_bf16<<<grid, 256, 0, stream>>>(A1, lda1, K1, A2, lda2, WT, bias, rs,
                                            C, ldc, n, Ktot, act, outf32);
    };

    // pre_mp
    gemm(xb, 128, 128, xb, 128, pre_wt, pre_b, nullptr, emb, 512, 128, 128, 0, 0);

    const int ggrid = (int)(((long long)n * 64 + 255) / 256);
    for (int l = 0; l < 4; ++l) {
        int K = 128 * (l + 1);
        gemm(emb, 512, K, emb, 512, c_wt[l], nullptr, dinv, g, 128, K, 128, 0, 0);
        bf16* out = (l < 3) ? (emb + (size_t)128 * (l + 1)) : h4;
        int ldo = (l < 3) ? 512 : 128;
        gcn_gather<<<ggrid, 256, 0, stream>>>(rp, csr, g, dinv, conv_b[l], out, ldo, n);
    }

    // post_mp
    gemm(emb, 512, 512, h4, 128, p1_wt, post_b1, nullptr, h1, 128, 640, 128, 2, 0);
    gemm(h1, 128, 128, h1, 128, p2_wt, post_b2, nullptr, h2, 128, 128, 128, 1, 0);
    gemm(h2, 128, 128, h2, 128, p3_wt, post_b3, nullptr, h3, 256, 128, 256, 1, 0);
    gemm(h3, 256, 256, h3, 256, p4_wt, post_b4, nullptr, d_out, 128, 256, 128, 0, 1);
}

// Round 7
// 805.330 us; speedup vs baseline: 14.8435x; 1.0093x over previous
//
#include <hip/hip_runtime.h>

// ---------------------------------------------------------------------------
// GeneralGNN: 4-layer GCN (skip='all') + MLP head.
// Round 6: packed 16-bit degree histogram (half the atomic line churn),
// fused weight-transpose kernel (1 launch instead of 9), gather ILP-4.
// ---------------------------------------------------------------------------

typedef __bf16 bf16;
typedef __attribute__((ext_vector_type(8))) __bf16 bf16x8;
typedef __attribute__((ext_vector_type(4))) __bf16 bf16x4;
typedef __attribute__((ext_vector_type(4))) float f32x4;

// ---------------- CSR build ----------------
__global__ __launch_bounds__(256) void zero_int(unsigned int* p, int n) {
    int i = blockIdx.x * 256 + threadIdx.x;
    if (i < n) p[i] = 0u;
}

// packed: cnt word dst>>1, halfword dst&1. rank[e] = old count for this dst.
__global__ __launch_bounds__(256) void hist_dst(const int* __restrict__ ei,
                                                unsigned int* cnt, int* __restrict__ rank, int E) {
    int e = blockIdx.x * 256 + threadIdx.x;
    if (e < E) {
        int dst = ei[E + e];
        int sh = (dst & 1) * 16;
        unsigned int old = atomicAdd(&cnt[dst >> 1], 1u << sh);
        rank[e] = (int)((old >> sh) & 0xFFFFu);
    }
}

// level 1: per-block scan of 2048 counts (1024 packed words) + block sums.
// Also emits dinv[i] = rsqrt(cnt[i]+1).
__global__ __launch_bounds__(256) void scan1(const unsigned int* __restrict__ cntp,
                                             int* __restrict__ rp,
                                             float* __restrict__ dinv,
                                             int* __restrict__ bsum, int nw) {
    __shared__ int sums[256];
    const int t = threadIdx.x;
    const int wbase = blockIdx.x * 1024 + t * 4;     // word index (x4)
    uint4 v = make_uint4(0u, 0u, 0u, 0u);
    if (wbase < nw) v = *(const uint4*)&cntp[wbase]; // nw % 4 == 0
    int c[8];
    c[0] = v.x & 0xFFFFu; c[1] = v.x >> 16;
    c[2] = v.y & 0xFFFFu; c[3] = v.y >> 16;
    c[4] = v.z & 0xFFFFu; c[5] = v.z >> 16;
    c[6] = v.w & 0xFFFFu; c[7] = v.w >> 16;
    int s = 0;
#pragma unroll
    for (int j = 0; j < 8; ++j) s += c[j];
    sums[t] = s;
    __syncthreads();
#pragma unroll
    for (int off = 1; off < 256; off <<= 1) {
        int u = (t >= off) ? sums[t - off] : 0;
        __syncthreads();
        sums[t] += u;
        __syncthreads();
    }
    int run = sums[t] - s;   // exclusive prefix within block
    if (wbase < nw) {
        const int ebase = wbase * 2;
        int r[8];
        float dv[8];
#pragma unroll
        for (int j = 0; j < 8; ++j) {
            r[j] = run;
            run += c[j];
            dv[j] = rsqrtf((float)(c[j] + 1));
        }
        *(int4*)&rp[ebase]     = make_int4(r[0], r[1], r[2], r[3]);
        *(int4*)&rp[ebase + 4] = make_int4(r[4], r[5], r[6], r[7]);
        *(float4*)&dinv[ebase]     = make_float4(dv[0], dv[1], dv[2], dv[3]);
        *(float4*)&dinv[ebase + 4] = make_float4(dv[4], dv[5], dv[6], dv[7]);
    }
    if (t == 255) bsum[blockIdx.x] = sums[255];
}

// level 2: single block, exclusive scan of nb block sums (nb <= 128)
__global__ __launch_bounds__(128) void scan2(int* __restrict__ bsum, int nb) {
    __shared__ int sums[128];
    const int t = threadIdx.x;
    int s = (t < nb) ? bsum[t] : 0;
    sums[t] = s;
    __syncthreads();
#pragma unroll
    for (int off = 1; off < 128; off <<= 1) {
        int u = (t >= off) ? sums[t - off] : 0;
        __syncthreads();
        sums[t] += u;
        __syncthreads();
    }
    if (t < nb) bsum[t] = sums[t] - s;   // exclusive
}

// level 3: add block offsets (2048 elems per block); writes sentinel rp[n]=E
__global__ __launch_bounds__(256) void scan3(int* __restrict__ rp,
                                             const int* __restrict__ bsum, int n, int E) {
    const int base = blockIdx.x * 2048 + threadIdx.x * 8;
    if (base < n) {
        int o = bsum[blockIdx.x];
        int4 a = *(int4*)&rp[base];
        int4 b = *(int4*)&rp[base + 4];
        a.x += o; a.y += o; a.z += o; a.w += o;
        b.x += o; b.y += o; b.z += o; b.w += o;
        *(int4*)&rp[base] = a;
        *(int4*)&rp[base + 4] = b;
    }
    if (blockIdx.x == 0 && threadIdx.x == 0) rp[n] = E;
}

// csr[rp[dst] + rank[e]] = src  — no atomics, 4 independent edges per thread
__global__ __launch_bounds__(256) void csr_fill(const int* __restrict__ ei,
                                                const int* __restrict__ rp,
                                                const int* __restrict__ rank,
                                                int* __restrict__ csr, int E) {
    const int T = gridDim.x * 256;
    int e = blockIdx.x * 256 + threadIdx.x;
#pragma unroll 4
    for (int i = 0; i < 4; ++i) {
        if (e < E) csr[rp[ei[E + e]] + rank[e]] = ei[e];
        e += T;
    }
}

// ---------------- casts ----------------
__global__ __launch_bounds__(256) void cast_f32_bf16(const float* __restrict__ in,
                                                     bf16* __restrict__ out, long long n4) {
    long long i = (long long)blockIdx.x * 256 + threadIdx.x;
    if (i < n4) {
        float4 v = ((const float4*)in)[i];
        bf16x4 o = {(bf16)v.x, (bf16)v.y, (bf16)v.z, (bf16)v.w};
        ((bf16x4*)out)[i] = o;
    }
}

// all 9 weight transposes in one launch: wt[cum[s] + nn*K + k] = src[s][k*N+nn]
struct TAll {
    const float* src[9];
    int cum[10];
    int N[9];
    int K[9];
};
__global__ __launch_bounds__(256) void transpose_all(TAll d, bf16* __restrict__ wt, int total) {
    int idx = blockIdx.x * 256 + threadIdx.x;
    if (idx >= total) return;
    int seg = 0;
#pragma unroll
    for (int s = 1; s < 9; ++s) if (idx >= d.cum[s]) seg = s;
    int local = idx - d.cum[seg];
    int N = d.N[seg], K = d.K[seg];
    int k = local / N;
    int nn = local - k * N;
    wt[d.cum[seg] + (size_t)nn * K + k] = (bf16)d.src[seg][local];
}

// ---------------- bf16 MFMA GEMM ----------------
// C[M,N] = act( rowscale * ([A1|A2][M,Ktot] @ WT^T) + bias )
// Tile 128x128, BK=64, 4 waves (2x2). global_load_lds width=16 staging:
// linear LDS dest, global source pre-swizzled by chunk ^= (row&7); fragment
// reads apply the same XOR (bank-conflict-free, both-sides pattern).
__global__ __launch_bounds__(256) void gemm_bf16(
    const bf16* __restrict__ A1, int lda1, int K1,
    const bf16* __restrict__ A2, int lda2,
    const bf16* __restrict__ WT,
    const float* __restrict__ bias,
    const float* __restrict__ rowscale,
    void* __restrict__ Cout, int ldc, int M, int Ktot,
    int act, int outf32)
{
    __shared__ bf16 Als[128 * 64];
    __shared__ bf16 Bls[128 * 64];

    const int t = threadIdx.x;
    const int lane = t & 63;
    const int wid = t >> 6;
    const int wm = wid >> 1, wn = wid & 1;
    const int row0 = blockIdx.x * 128;
    const int col0 = blockIdx.y * 128;
    const int nt = Ktot >> 6;

    f32x4 acc[4][4];
#pragma unroll
    for (int mf = 0; mf < 4; ++mf)
#pragma unroll
        for (int nf = 0; nf < 4; ++nf) {
            f32x4 z = {0.f, 0.f, 0.f, 0.f};
            acc[mf][nf] = z;
        }

    int srow[4], scs[4];
#pragma unroll
    for (int i = 0; i < 4; ++i) {
        int ch = wid * 64 + i * 256 + lane;
        int row = ch >> 3, c = ch & 7;
        srow[i] = row;
        scs[i] = (c ^ (row & 7)) * 8;
    }

    for (int kt = 0; kt < nt; ++kt) {
        const int k0 = kt * 64;
        const bf16* Ap; int lda_, kk;
        if (k0 < K1) { Ap = A1; lda_ = lda1; kk = k0; }
        else         { Ap = A2; lda_ = lda2; kk = k0 - K1; }

        __syncthreads();
#pragma unroll
        for (int i = 0; i < 4; ++i) {
            int grow = row0 + srow[i]; if (grow >= M) grow = M - 1;
            const bf16* ga = &Ap[(size_t)grow * lda_ + kk + scs[i]];
            const bf16* gb = &WT[(size_t)(col0 + srow[i]) * Ktot + k0 + scs[i]];
            bf16* la = &Als[(size_t)(wid * 64 + i * 256) * 8];
            bf16* lb = &Bls[(size_t)(wid * 64 + i * 256) * 8];
            __builtin_amdgcn_global_load_lds(
                (const __attribute__((address_space(1))) void*)ga,
                (__attribute__((address_space(3))) void*)la, 16, 0, 0);
            __builtin_amdgcn_global_load_lds(
                (const __attribute__((address_space(1))) void*)gb,
                (__attribute__((address_space(3))) void*)lb, 16, 0, 0);
        }
        asm volatile("s_waitcnt vmcnt(0)" ::: "memory");
        __syncthreads();

#pragma unroll
        for (int ks = 0; ks < 2; ++ks) {
            bf16x8 af[4], bfr[4];
#pragma unroll
            for (int mf = 0; mf < 4; ++mf) {
                int r = wm * 64 + mf * 16 + (lane & 15);
                int ch = (ks * 4 + (lane >> 4)) ^ (r & 7);
                af[mf] = *(const bf16x8*)((const char*)Als + r * 128 + ch * 16);
            }
#pragma unroll
            for (int nf = 0; nf < 4; ++nf) {
                int r = wn * 64 + nf * 16 + (lane & 15);
                int ch = (ks * 4 + (lane >> 4)) ^ (r & 7);
                bfr[nf] = *(const bf16x8*)((const char*)Bls + r * 128 + ch * 16);
            }
#pragma unroll
            for (int mf = 0; mf < 4; ++mf)
#pragma unroll
                for (int nf = 0; nf < 4; ++nf)
                    acc[mf][nf] = __builtin_amdgcn_mfma_f32_16x16x32_bf16(
                        af[mf], bfr[nf], acc[mf][nf], 0, 0, 0);
        }
    }

#pragma unroll
    for (int mf = 0; mf < 4; ++mf) {
        int rbase = row0 + wm * 64 + mf * 16 + (lane >> 4) * 4;
#pragma unroll
        for (int nf = 0; nf < 4; ++nf) {
            int gcol = col0 + wn * 64 + nf * 16 + (lane & 15);
            float bv = bias ? bias[gcol] : 0.f;
#pragma unroll
            for (int i = 0; i < 4; ++i) {
                int grow = rbase + i;
                if (grow >= M) continue;
                float v = acc[mf][nf][i];
                if (rowscale) v *= rowscale[grow];
                v += bv;
                if (act == 1) v = fmaxf(v, 0.f);
                else if (act == 2) v = v > 0.f ? v : 0.1f * v;
                if (outf32) ((float*)Cout)[(size_t)grow * ldc + gcol] = v;
                else        ((bf16*)Cout)[(size_t)grow * ldc + gcol] = (bf16)v;
            }
        }
    }
}

// ---------------- fused gather ----------------
// wave per node; 4 groups x 16 lanes; 4 edges in flight per group (ILP-4).
__global__ __launch_bounds__(256) void gcn_gather(
    const int* __restrict__ rp, const int* __restrict__ csr,
    const bf16* __restrict__ g, const float* __restrict__ dinv,
    const float* __restrict__ b,
    bf16* __restrict__ out, int ldo, int n)
{
    const int node = (int)(((long long)blockIdx.x * 256 + threadIdx.x) >> 6);
    if (node >= n) return;
    const int lane = threadIdx.x & 63;
    const int grp = lane >> 4;
    const int cc = lane & 15;
    const int start = rp[node];
    const int end = rp[node + 1];

    float acc[8];
#pragma unroll
    for (int j = 0; j < 8; ++j) acc[j] = 0.f;

    int j = start + grp;
    for (; j + 12 < end; j += 16) {
        int s0 = csr[j];
        int s1 = csr[j + 4];
        int s2 = csr[j + 8];
        int s3 = csr[j + 12];
        bf16x8 v0 = *(const bf16x8*)&g[(size_t)s0 * 128 + cc * 8];
        bf16x8 v1 = *(const bf16x8*)&g[(size_t)s1 * 128 + cc * 8];
        bf16x8 v2 = *(const bf16x8*)&g[(size_t)s2 * 128 + cc * 8];
        bf16x8 v3 = *(const bf16x8*)&g[(size_t)s3 * 128 + cc * 8];
#pragma unroll
        for (int jj = 0; jj < 8; ++jj)
            acc[jj] += ((float)v0[jj] + (float)v1[jj]) + ((float)v2[jj] + (float)v3[jj]);
    }
    for (; j < end; j += 4) {
        int s0 = csr[j];
        bf16x8 v0 = *(const bf16x8*)&g[(size_t)s0 * 128 + cc * 8];
#pragma unroll
        for (int jj = 0; jj < 8; ++jj) acc[jj] += (float)v0[jj];
    }
#pragma unroll
    for (int jj = 0; jj < 8; ++jj) {
        acc[jj] += __shfl_xor(acc[jj], 16, 64);
        acc[jj] += __shfl_xor(acc[jj], 32, 64);
    }
    if (grp == 0) {
        bf16x8 sv = *(const bf16x8*)&g[(size_t)node * 128 + cc * 8];
        float s = dinv[node];
        bf16x8 o;
#pragma unroll
        for (int jj = 0; jj < 8; ++jj) {
            float v = fmaf(s, acc[jj] + (float)sv[jj], b[cc * 8 + jj]);
            o[jj] = (bf16)fmaxf(v, 0.f);
        }
        *(bf16x8*)&out[(size_t)node * ldo + cc * 8] = o;
    }
}

// ---------------- launcher ----------------
extern "C" void kernel_launch(void* const* d_in, const int* in_sizes, int n_in,
                              void* d_out, int out_size, void* d_ws, size_t ws_size,
                              hipStream_t stream) {
    const float* x      = (const float*)d_in[0];
    const int*   ei     = (const int*)d_in[1];
    const float* pre_w  = (const float*)d_in[2];
    const float* pre_b  = (const float*)d_in[3];
    const float* conv_w[4] = {(const float*)d_in[4], (const float*)d_in[6],
                              (const float*)d_in[8], (const float*)d_in[10]};
    const float* conv_b[4] = {(const float*)d_in[5], (const float*)d_in[7],
                              (const float*)d_in[9], (const float*)d_in[11]};
    const float* post_w1 = (const float*)d_in[12];
    const float* post_b1 = (const float*)d_in[13];
    const float* post_w2 = (const float*)d_in[14];
    const float* post_b2 = (const float*)d_in[15];
    const float* post_w3 = (const float*)d_in[16];
    const float* post_b3 = (const float*)d_in[17];
    const float* post_w4 = (const float*)d_in[18];
    const float* post_b4 = (const float*)d_in[19];

    const int n = in_sizes[0] / 128;    // 100000
    const int E = in_sizes[1] / 2;      // 1600000
    const int nw = n / 2;               // packed count words
    const int nb = (nw + 1023) / 1024;  // scan blocks (2048 counts each)

    // ws layout (bytes)
    size_t off = 0;
    bf16* emb  = (bf16*)((char*)d_ws + off); off += (size_t)n * 512 * 2;
    bf16* g    = (bf16*)((char*)d_ws + off); off += (size_t)n * 128 * 2;
    bf16* h4   = (bf16*)((char*)d_ws + off); off += (size_t)n * 128 * 2;
    bf16* xb   = (bf16*)((char*)d_ws + off); off += (size_t)n * 128 * 2;
    float* dinv = (float*)((char*)d_ws + off); off += (size_t)n * 4;
    int*   rp   = (int*)((char*)d_ws + off); off += (size_t)(n + 4) * 4;
    int*   csr  = (int*)((char*)d_ws + off); off += (size_t)E * 4;
    int*   rank = (int*)((char*)d_ws + off); off += (size_t)E * 4;
    bf16*  wt   = (bf16*)((char*)d_ws + off); off += (size_t)344064 * 2;
    int*   bsum = (int*)((char*)d_ws + off); off += 128 * 4;
    if (ws_size < off) return;  // diagnostic early-out

    unsigned int* cnt = (unsigned int*)dinv;   // packed overlay during CSR build
    bf16* h1 = g;               // post overlays on dead buffers
    bf16* h2 = xb;
    bf16* h3 = emb;

    // weight-pool offsets (elements)
    bf16* pre_wt  = wt;            // [128][128]
    bf16* c_wt0   = wt + 16384;
    bf16* c_wt1   = wt + 32768;
    bf16* c_wt2   = wt + 65536;
    bf16* c_wt3   = wt + 114688;
    bf16* p1_wt   = wt + 180224;   // [128][640]
    bf16* p2_wt   = wt + 262144;
    bf16* p3_wt   = wt + 278528;   // [256][128]
    bf16* p4_wt   = wt + 311296;   // [128][256]
    bf16* c_wt[4] = {c_wt0, c_wt1, c_wt2, c_wt3};

    // ---- CSR build ----
    zero_int<<<(nw + 255) / 256, 256, 0, stream>>>(cnt, nw);
    hist_dst<<<(E + 255) / 256, 256, 0, stream>>>(ei, cnt, rank, E);
    scan1<<<nb, 256, 0, stream>>>(cnt, rp, dinv, bsum, nw);
    scan2<<<1, 128, 0, stream>>>(bsum, nb);
    scan3<<<nb, 256, 0, stream>>>(rp, bsum, n, E);
    csr_fill<<<(E / 4 + 255) / 256, 256, 0, stream>>>(ei, rp, rank, csr, E);

    // ---- casts (x) + all weight transposes in one launch ----
    cast_f32_bf16<<<(int)(((long long)n * 32 + 255) / 256), 256, 0, stream>>>(x, xb, (long long)n * 32);
    TAll ta;
    ta.src[0] = pre_w;   ta.K[0] = 128; ta.N[0] = 128;
    ta.src[1] = conv_w[0]; ta.K[1] = 128; ta.N[1] = 128;
    ta.src[2] = conv_w[1]; ta.K[2] = 256; ta.N[2] = 128;
    ta.src[3] = conv_w[2]; ta.K[3] = 384; ta.N[3] = 128;
    ta.src[4] = conv_w[3]; ta.K[4] = 512; ta.N[4] = 128;
    ta.src[5] = post_w1;  ta.K[5] = 640; ta.N[5] = 128;
    ta.src[6] = post_w2;  ta.K[6] = 128; ta.N[6] = 128;
    ta.src[7] = post_w3;  ta.K[7] = 128; ta.N[7] = 256;
    ta.src[8] = post_w4;  ta.K[8] = 256; ta.N[8] = 128;
    ta.cum[0] = 0;
    for (int s = 0; s < 9; ++s) ta.cum[s + 1] = ta.cum[s] + ta.K[s] * ta.N[s];
    const int wtot = ta.cum[9];   // 344064
    transpose_all<<<(wtot + 255) / 256, 256, 0, stream>>>(ta, wt, wtot);

    const int gx = (n + 127) / 128;
    auto gemm = [&](const bf16* A1, int lda1, int K1, const bf16* A2, int lda2,
                    const bf16* WT, const float* bias, const float* rs,
                    void* C, int ldc, int Ktot, int N, int act, int outf32) {
        dim3 grid(gx, N / 128);
        gemm_bf16<<<grid, 256, 0, stream>>>(A1, lda1, K1, A2, lda2, WT, bias, rs,
                                            C, ldc, n, Ktot, act, outf32);
    };

    // pre_mp
    gemm(xb, 128, 128, xb, 128, pre_wt, pre_b, nullptr, emb, 512, 128, 128, 0, 0);

    const int ggrid = (int)(((long long)n * 64 + 255) / 256);
    for (int l = 0; l < 4; ++l) {
        int K = 128 * (l + 1);
        gemm(emb, 512, K, emb, 512, c_wt[l], nullptr, dinv, g, 128, K, 128, 0, 0);
        bf16* out = (l < 3) ? (emb + (size_t)128 * (l + 1)) : h4;
        int ldo = (l < 3) ? 512 : 128;
        gcn_gather<<<ggrid, 256, 0, stream>>>(rp, csr, g, dinv, conv_b[l], out, ldo, n);
    }

    // post_mp
    gemm(emb, 512, 512, h4, 128, p1_wt, post_b1, nullptr, h1, 128, 640, 128, 2, 0);
    gemm(h1, 128, 128, h1, 128, p2_wt, post_b2, nullptr, h2, 128, 128, 128, 1, 0);
    gemm(h2, 128, 128, h2, 128, p3_wt, post_b3, nullptr, h3, 256, 128, 256, 1, 0);
    gemm(h3, 256, 256, h3, 256, p4_wt, post_b4, nullptr, d_out, 128, 256, 128, 0, 1);
}